// Round 7
// baseline (4879.113 us; speedup 1.0000x reference)
//
#include <hip/hip_runtime.h>
#include <hip/hip_bf16.h>
#include <hip/hip_fp16.h>
#include <math.h>

#define HH    1024
#define TT    64
#define NBAT  256
#define G3    3072
#define IN0   150
#define IN0P  160   // padded K for layer 0
#define NCLS  60
#define ENC_W 2048

typedef float  f32x4 __attribute__((ext_vector_type(4)));
typedef short  s16x8 __attribute__((ext_vector_type(8)));

#define GLOAD16(gsrc, ldst) \
  __builtin_amdgcn_global_load_lds((const __attribute__((address_space(1))) unsigned int*)(gsrc), \
                                   (__attribute__((address_space(3))) unsigned int*)(ldst), 16, 0, 0)

static __device__ inline short f2bf(float f) {
    __hip_bfloat16 h = __float2bfloat16(f);
    return *(short*)&h;
}

// ---------------- BatchNorm stats ----------------
__global__ void bigru_bn_stats(const float* __restrict__ x,
                               float* __restrict__ mean, float* __restrict__ istd) {
    int f = blockIdx.x;
    int tid = threadIdx.x;
    double s = 0.0, s2 = 0.0;
    for (int i = tid; i < NBAT * TT; i += blockDim.x) {
        float v = x[(size_t)i * IN0 + f];
        s += v; s2 += (double)v * v;
    }
    __shared__ double sh[256], sh2[256];
    sh[tid] = s; sh2[tid] = s2;
    __syncthreads();
    for (int off = 128; off > 0; off >>= 1) {
        if (tid < off) { sh[tid] += sh[tid + off]; sh2[tid] += sh2[tid + off]; }
        __syncthreads();
    }
    if (tid == 0) {
        double m = sh[0] / (NBAT * TT);
        double var = sh2[0] / (NBAT * TT) - m * m;
        mean[f] = (float)m;
        istd[f] = (float)(1.0 / sqrt(var + 1e-5));
    }
}

// ---------------- BN apply -> padded bf16 [16384][160] ----------------
__global__ void bigru_bn_apply_bf16(const float* __restrict__ x,
                                    const float* __restrict__ mean, const float* __restrict__ istd,
                                    const float* __restrict__ gamma, const float* __restrict__ beta,
                                    short* __restrict__ xn) {
    int idx = blockIdx.x * blockDim.x + threadIdx.x;
    if (idx >= NBAT * TT * IN0P) return;
    int f = idx % IN0P;
    int r = idx / IN0P;
    float v = 0.f;
    if (f < IN0) v = (x[(size_t)r * IN0 + f] - mean[f]) * istd[f] * gamma[f] + beta[f];
    xn[idx] = f2bf(v);
}

// ---------------- Convert w_ih_0 [2][3072][150] -> padded bf16 [2][3072][160] ----
__global__ void bigru_cvt_wih0(const float* __restrict__ src, short* __restrict__ dst) {
    int idx = blockIdx.x * blockDim.x + threadIdx.x;
    if (idx >= 2 * G3 * IN0P) return;
    int f = idx % IN0P;
    int r = idx / IN0P;
    float v = (f < IN0) ? src[(size_t)r * IN0 + f] : 0.f;
    dst[idx] = f2bf(v);
}

// ---------------- Generic f32 -> bf16 convert (n % 4 == 0) ----------------
__global__ void bigru_cvt4(const float* __restrict__ src, short* __restrict__ dst, int n4) {
    int i = blockIdx.x * blockDim.x + threadIdx.x;
    if (i >= n4) return;
    float4 v = ((const float4*)src)[i];
    short4 o;
    o.x = f2bf(v.x); o.y = f2bf(v.y); o.z = f2bf(v.z); o.w = f2bf(v.w);
    ((short4*)dst)[i] = o;
}

// ---------------- Bulk gi GEMM: C[2][Mchunk][3072] = A @ W^T + b_ih (fp16 out) ----
__global__ __launch_bounds__(256)
void bigru_gi_gemm(const short* __restrict__ Abase, int ldA, int K,
                   const short* __restrict__ W,       // [2][3072][K]
                   const float* __restrict__ b_ih,    // [2][3072]
                   __half* __restrict__ gi,           // [2][Mchunk][3072] fp16
                   int t0, int Mchunk) {
    int d    = blockIdx.z;
    int col0 = blockIdx.x * 128;
    int row0 = blockIdx.y * 128;

    __shared__ short As[128][32];
    __shared__ short Bs[128][32];

    int tid  = threadIdx.x;
    int lane = tid & 63;
    int w    = tid >> 6;
    int wm   = w & 1, wn = w >> 1;

    f32x4 acc[4][4];
    #pragma unroll
    for (int i = 0; i < 4; ++i)
        #pragma unroll
        for (int j = 0; j < 4; ++j)
            acc[i][j] = (f32x4){0.f, 0.f, 0.f, 0.f};

    const short* Wd = W + (size_t)d * G3 * K;
    int sr = lane >> 2;
    int sc = (lane & 3) * 8;

    for (int k0 = 0; k0 < K; k0 += 32) {
        #pragma unroll
        for (int q = 0; q < 2; ++q) {
            int r  = w * 32 + q * 16 + sr;            // 0..127
            int gr = row0 + r;
            int tt = gr >> 8, n = gr & 255;
            const short* ga = Abase + (size_t)(n * TT + t0 + tt) * ldA + k0 + sc;
            GLOAD16(ga, &As[w * 32 + q * 16][0]);
            const short* gb = Wd + (size_t)(col0 + r) * K + k0 + sc;
            GLOAD16(gb, &Bs[w * 32 + q * 16][0]);
        }
        __syncthreads();

        int fr = lane & 15, fq = (lane >> 4) * 8;
        s16x8 a[4], b[4];
        #pragma unroll
        for (int i = 0; i < 4; ++i) a[i] = *(const s16x8*)&As[wm * 64 + i * 16 + fr][fq];
        #pragma unroll
        for (int j = 0; j < 4; ++j) b[j] = *(const s16x8*)&Bs[wn * 64 + j * 16 + fr][fq];
        #pragma unroll
        for (int i = 0; i < 4; ++i)
            #pragma unroll
            for (int j = 0; j < 4; ++j)
                acc[i][j] = __builtin_amdgcn_mfma_f32_16x16x32_bf16(a[i], b[j], acc[i][j], 0, 0, 0);
        __syncthreads();
    }

    int fr = lane & 15, quad = lane >> 4;
    #pragma unroll
    for (int j = 0; j < 4; ++j) {
        int c = col0 + wn * 64 + j * 16 + fr;
        float bias = b_ih[d * G3 + c];
        #pragma unroll
        for (int i = 0; i < 4; ++i) {
            #pragma unroll
            for (int reg = 0; reg < 4; ++reg) {
                int r = row0 + wm * 64 + i * 16 + quad * 4 + reg;
                gi[((size_t)d * Mchunk + r) * G3 + c] = __float2half(acc[i][j][reg] + bias);
            }
        }
    }
}

// ---------------- Fused persistent recurrence over Tc steps (v7) ----------------
// 256 blocks x 256 threads (4 waves). Block b: d=b&1, mt=(b>>1)&1, ct=b>>2.
// Wave w owns 32 rows (row_base = mt*128 + w*32) -> each B fragment read from
// LDS feeds TWO MFMAs (rows fr, fr+16): B LDS traffic halved vs 8x16 (v6's
// dominant cost term). LDS = 96 KiB W + 32 KiB A ring (4 waves x 4 slots x 2KB)
// = 128 KiB. Each slot = one 32-wide k-chunk for 32 rows, filled by TWO
// GLOAD16; steady wait vmcnt(4), drain (2)/(0) at c=30/31.
// gi is fp16 (halves HBM traffic). Barrier: v6 per-block flag scheme.
__global__ __launch_bounds__(256, 1)
void bigru_steps_fused(const short* __restrict__ w_hh,   // [2][3072][1024] bf16
                       const float* __restrict__ b_hh,   // [2][3072]
                       const __half* __restrict__ gi,    // [2][Mchunk][3072] fp16
                       float* __restrict__ h,            // [2][256][1024] fp32 master
                       short* __restrict__ hbf,          // [2buf][2][256][1024] bf16
                       float* __restrict__ enc,          // non-null only on last layer
                       short* __restrict__ enc_bf,       // null on last layer
                       unsigned int* __restrict__ bar,   // [4 groups][64 flags][32 uints]
                       int t0, int Tc, int Mchunk) {
    __shared__ short Ws[48 * 1024];     // 96 KiB persistent W slice
    __shared__ short As[4][4][1024];    // 32 KiB A ring: 4 waves x 4 slots x 2KB

    int b   = blockIdx.x;
    int d   = b & 1;
    int mt  = (b >> 1) & 1;
    int ct  = b >> 2;              // 0..63 (= flag slot in group)
    int grp = b & 3;

    int tid  = threadIdx.x;
    int lane = tid & 63;
    int w    = tid >> 6;           // 0..3
    int fr   = lane & 15;
    int quad = lane >> 4;
    int sw   = fr & 7;

    int j0 = ct * 16;
    int row_base = mt * 128 + w * 32;   // wave owns 32 rows
    int jcol = j0 + fr;

    const short* Wd = w_hh + (size_t)d * G3 * HH;

    // ---- stage W slice into LDS once (pre-swizzled source, linear dest) ----
    #pragma unroll
    for (int q = 0; q < 24; ++q) {
        int c  = w * 24 + q;               // 0..95
        int rr = c >> 1, kh = c & 1;       // rr: wrow 0..47, kh: half-row
        int g  = rr >> 4, jc = rr & 15;
        const short* src = Wd + (size_t)(g * HH + j0 + jc) * HH
                         + (size_t)(kh * 64 + (lane ^ (rr & 7))) * 8;
        GLOAD16(src, &Ws[rr * 1024 + kh * 512]);
    }

    // ---- per-lane pre-swizzled A source mapping (linear DMA dest decode) ----
    // dest byte = lane*16; decode through byte^=((row&7)<<4) swizzle:
    int l0 = lane & 1, l1 = (lane >> 1) & 1, l2 = (lane >> 2) & 1;
    int l3 = (lane >> 3) & 1, l4 = (lane >> 4) & 1, l5 = (lane >> 5) & 1;
    int arow = (l2 ^ l4) | (l3 << 1) | (l4 << 2) | (l5 << 3);   // 0..15
    int akb  = (l0 ^ l2 ^ l4) | ((l1 ^ l3) << 1);               // 0..3
    // two DMA source streams per wave: rows [0,16) and [16,32) of the 32-row slab
    size_t a_src0 = (size_t)(row_base + arow) * HH + (size_t)akb * 8;       // shorts
    size_t a_src1 = (size_t)(row_base + 16 + arow) * HH + (size_t)akb * 8;  // shorts

    // ---- persistent h registers: 2 row-frags x 4 ----
    float hreg[2][4];
    #pragma unroll
    for (int hh = 0; hh < 2; ++hh)
        #pragma unroll
        for (int r = 0; r < 4; ++r) {
            int n = row_base + hh * 16 + quad * 4 + r;
            hreg[hh][r] = h[((size_t)d * NBAT + n) * HH + jcol];
        }
    float bhr = b_hh[d * G3 + jcol];
    float bhz = b_hh[d * G3 + HH + jcol];
    float bhn = b_hh[d * G3 + 2 * HH + jcol];

    __syncthreads();   // W staged (syncthreads drains vmcnt)

    // gi for step 0 (pipelined across barrier for later steps)
    float gir[2][4], giz[2][4], gin[2][4];
    {
        size_t gb0 = ((size_t)d * Mchunk) * G3 + jcol;
        #pragma unroll
        for (int hh = 0; hh < 2; ++hh)
            #pragma unroll
            for (int r = 0; r < 4; ++r) {
                int n = row_base + hh * 16 + quad * 4 + r;
                size_t gg = gb0 + (size_t)n * G3;
                gir[hh][r] = __half2float(gi[gg]);
                giz[hh][r] = __half2float(gi[gg + HH]);
                gin[hh][r] = __half2float(gi[gg + 2 * HH]);
            }
    }

    for (int tt = 0; tt < Tc; ++tt) {
        int t = t0 + tt;
        const short* hb = hbf + ((size_t)((t & 1) * 2 + d)) * NBAT * HH;
        short*       ho = hbf + ((size_t)(((t + 1) & 1) * 2 + d)) * NBAT * HH;
        const short* asrc0 = hb + a_src0;
        const short* asrc1 = hb + a_src1;

        f32x4 acc[2][3];
        #pragma unroll
        for (int hh = 0; hh < 2; ++hh)
            #pragma unroll
            for (int g = 0; g < 3; ++g)
                acc[hh][g] = (f32x4){0.f, 0.f, 0.f, 0.f};

        // prologue: 3 slots (6 DMA instrs) in flight
        #pragma unroll
        for (int c = 0; c < 3; ++c) {
            GLOAD16(asrc0 + c * 32, &As[w][c][0]);
            GLOAD16(asrc1 + c * 32, &As[w][c][512]);
        }

        int rd_off = (fr * 64 + quad * 16) ^ ((fr & 7) << 4);   // swizzled A read (bytes)

        #pragma unroll
        for (int c = 0; c < 32; ++c) {
            // slot c complete when outstanding <= 2*min(31-c,2)... schedule:
            // c<=29: slots c+1,c+2 may remain -> vmcnt(4); c==30: vmcnt(2); c==31: vmcnt(0)
            if (c < 30)       asm volatile("s_waitcnt vmcnt(4)");
            else if (c == 30) asm volatile("s_waitcnt vmcnt(2)");
            else              asm volatile("s_waitcnt vmcnt(0)");
            __builtin_amdgcn_sched_barrier(0);
            const char* slot = (const char*)&As[w][c & 3][0];
            s16x8 a0 = *(const s16x8*)(slot + rd_off);
            s16x8 a1 = *(const s16x8*)(slot + 1024 + rd_off);
            int ks = c * 4 + quad;
            #pragma unroll
            for (int g = 0; g < 3; ++g) {
                s16x8 bg = *(const s16x8*)&Ws[(g * 16 + fr) * 1024 + ((ks ^ sw) << 3)];
                acc[0][g] = __builtin_amdgcn_mfma_f32_16x16x32_bf16(a0, bg, acc[0][g], 0, 0, 0);
                acc[1][g] = __builtin_amdgcn_mfma_f32_16x16x32_bf16(a1, bg, acc[1][g], 0, 0, 0);
            }
            __builtin_amdgcn_sched_barrier(0);
            if (c + 3 < 32) {
                GLOAD16(asrc0 + (c + 3) * 32, &As[w][(c + 3) & 3][0]);
                GLOAD16(asrc1 + (c + 3) * 32, &As[w][(c + 3) & 3][512]);
            }
        }

        // ---- gates + state update (2 row-frags) ----
        #pragma unroll
        for (int hh = 0; hh < 2; ++hh) {
            #pragma unroll
            for (int r = 0; r < 4; ++r) {
                int n = row_base + hh * 16 + quad * 4 + r;
                float hrv = acc[hh][0][r] + bhr;
                float hzv = acc[hh][1][r] + bhz;
                float hnv = acc[hh][2][r] + bhn;
                float rg = 1.f / (1.f + __expf(-(gir[hh][r] + hrv)));
                float zg = 1.f / (1.f + __expf(-(giz[hh][r] + hzv)));
                float ng = tanhf(gin[hh][r] + rg * hnv);
                float hnew = (1.f - zg) * ng + zg * hreg[hh][r];
                hreg[hh][r] = hnew;
                ho[(size_t)n * HH + jcol] = f2bf(hnew);
                size_t eidx = ((size_t)n * TT + t) * ENC_W + (size_t)d * HH + jcol;
                if (enc_bf) enc_bf[eidx] = f2bf(hnew);
                if (enc)    enc[eidx]    = hnew;
            }
        }

        if (tt == Tc - 1) {   // persist fp32 h for the next chunk
            #pragma unroll
            for (int hh = 0; hh < 2; ++hh)
                #pragma unroll
                for (int r = 0; r < 4; ++r) {
                    int n = row_base + hh * 16 + quad * 4 + r;
                    h[((size_t)d * NBAT + n) * HH + jcol] = hreg[hh][r];
                }
        } else {
            // prefetch next step's gi BEFORE the barrier: HBM latency overlaps spin
            size_t gbn = ((size_t)d * Mchunk + (size_t)(tt + 1) * NBAT) * G3 + jcol;
            #pragma unroll
            for (int hh = 0; hh < 2; ++hh)
                #pragma unroll
                for (int r = 0; r < 4; ++r) {
                    int n = row_base + hh * 16 + quad * 4 + r;
                    size_t gg = gbn + (size_t)n * G3;
                    gir[hh][r] = __half2float(gi[gg]);
                    giz[hh][r] = __half2float(gi[gg + HH]);
                    gin[hh][r] = __half2float(gi[gg + 2 * HH]);
                }
            // ---- flag barrier over the 64 blocks of group (d, mt) ----
            __syncthreads();                       // all waves' stores drained
            if (w == 0) {
                unsigned int* fl = bar + (size_t)grp * 64 * 32;
                unsigned tgt = (unsigned)(tt + 1);
                if (lane == 0)
                    __hip_atomic_store(&fl[ct * 32], tgt,
                                       __ATOMIC_RELEASE, __HIP_MEMORY_SCOPE_AGENT);
                for (;;) {
                    unsigned v = __hip_atomic_load(&fl[lane * 32],
                                                   __ATOMIC_ACQUIRE, __HIP_MEMORY_SCOPE_AGENT);
                    if (__all(v >= tgt)) break;
                    __builtin_amdgcn_s_sleep(2);
                }
            }
            __syncthreads();
        }
    }
}

// ---------------- FC head ----------------
__global__ void bigru_fc(const float* __restrict__ enc, const float* __restrict__ fc_w,
                         const float* __restrict__ fc_b, float* __restrict__ out) {
    int n = blockIdx.x;
    int tid = threadIdx.x;
    __shared__ float hbuf[ENC_W];
    for (int k = tid; k < ENC_W; k += blockDim.x)
        hbuf[k] = enc[(size_t)n * TT * ENC_W + (size_t)(TT - 1) * ENC_W + k];
    __syncthreads();
    if (tid < NCLS) {
        float acc = fc_b[tid];
        for (int k = 0; k < ENC_W; ++k)
            acc += hbuf[k] * fc_w[(size_t)tid * ENC_W + k];
        out[(size_t)n * NCLS + tid] = acc;
    }
}

extern "C" void kernel_launch(void* const* d_in, const int* in_sizes, int n_in,
                              void* d_out, int out_size, void* d_ws, size_t ws_size,
                              hipStream_t stream) {
    const float* x        = (const float*)d_in[0];
    const float* bn_gamma = (const float*)d_in[1];
    const float* bn_beta  = (const float*)d_in[2];
    const float* w_ih[3]  = {(const float*)d_in[3], (const float*)d_in[7],  (const float*)d_in[11]};
    const float* w_hh[3]  = {(const float*)d_in[4], (const float*)d_in[8],  (const float*)d_in[12]};
    const float* b_ih[3]  = {(const float*)d_in[5], (const float*)d_in[9],  (const float*)d_in[13]};
    const float* b_hh[3]  = {(const float*)d_in[6], (const float*)d_in[10], (const float*)d_in[14]};
    const float* fc_w     = (const float*)d_in[15];
    const float* fc_b     = (const float*)d_in[16];

    float* out = (float*)d_out;
    float* enc = out + NBAT * NCLS;                       // [256][64][2048] fp32

    // ---- workspace bump allocator (256B aligned) ----
    char* base = (char*)d_ws;
    size_t off = 0;
    auto alloc = [&](size_t bytes) {
        void* p = base + off;
        off += (bytes + 255) & ~(size_t)255;
        return p;
    };
    float* mean      = (float*)alloc(IN0 * 4);
    float* istd      = (float*)alloc(IN0 * 4);
    short* xn_bf     = (short*)alloc((size_t)NBAT * TT * IN0P * 2);
    short* wih0_bf   = (short*)alloc((size_t)2 * G3 * IN0P * 2);
    short* wih_bf    = (short*)alloc((size_t)2 * G3 * ENC_W * 2);
    short* whh_bf    = (short*)alloc((size_t)2 * G3 * HH * 2);
    float* h         = (float*)alloc((size_t)2 * NBAT * HH * 4);
    short* hbf       = (short*)alloc((size_t)2 * 2 * NBAT * HH * 2);  // double buffer
    short* enc_bf    = (short*)alloc((size_t)NBAT * TT * ENC_W * 2);
    unsigned int* bar = (unsigned int*)alloc((size_t)4 * 64 * 32 * sizeof(unsigned int));
    size_t fixed = off;

    // pick largest Tc whose fp16 gi chunk fits in remaining ws
    int Tc = 1;
    for (int cand : {16, 8, 4, 2, 1}) {
        size_t gi_bytes = (size_t)2 * NBAT * cand * G3 * 2;
        if (fixed + gi_bytes + 1024 <= ws_size) { Tc = cand; break; }
    }
    __half* gi = (__half*)alloc((size_t)2 * NBAT * Tc * G3 * 2);
    int Mchunk = NBAT * Tc;

    // ---- BN ----
    bigru_bn_stats<<<IN0, 256, 0, stream>>>(x, mean, istd);
    bigru_bn_apply_bf16<<<(NBAT * TT * IN0P + 255) / 256, 256, 0, stream>>>(
        x, mean, istd, bn_gamma, bn_beta, xn_bf);

    // ---- weight conversions (layer-0 padded) ----
    bigru_cvt_wih0<<<(2 * G3 * IN0P + 255) / 256, 256, 0, stream>>>(w_ih[0], wih0_bf);

    for (int l = 0; l < 3; ++l) {
        if (l > 0) {
            int n4 = (2 * G3 * ENC_W) / 4;
            bigru_cvt4<<<(n4 + 255) / 256, 256, 0, stream>>>(w_ih[l], wih_bf, n4);
        }
        {
            int n4 = (2 * G3 * HH) / 4;
            bigru_cvt4<<<(n4 + 255) / 256, 256, 0, stream>>>(w_hh[l], whh_bf, n4);
        }
        hipMemsetAsync(h, 0, (size_t)2 * NBAT * HH * 4, stream);
        hipMemsetAsync(hbf, 0, (size_t)2 * 2 * NBAT * HH * 2, stream);

        const short* Abase = (l == 0) ? xn_bf : enc_bf;
        int ldA = (l == 0) ? IN0P : ENC_W;
        int K   = (l == 0) ? IN0P : ENC_W;
        const short* W = (l == 0) ? wih0_bf : wih_bf;

        for (int t0 = 0; t0 < TT; t0 += Tc) {
            bigru_gi_gemm<<<dim3(G3 / 128, Mchunk / 128, 2), 256, 0, stream>>>(
                Abase, ldA, K, W, b_ih[l], gi, t0, Mchunk);

            hipMemsetAsync(bar, 0, (size_t)4 * 64 * 32 * sizeof(unsigned int), stream);

            const short* whh_c   = whh_bf;
            const float* bhh_c   = b_hh[l];
            const __half* gi_c   = gi;
            float*       h_c     = h;
            short*       hbf_c   = hbf;
            float*       enc_c   = (l == 2) ? enc : nullptr;
            short*       encbf_c = (l == 2) ? nullptr : enc_bf;
            unsigned int* bar_c  = bar;
            int a_t0 = t0, a_tc = Tc, a_mc = Mchunk;
            void* kargs[] = { &whh_c, &bhh_c, &gi_c, &h_c, &hbf_c,
                              &enc_c, &encbf_c, &bar_c, &a_t0, &a_tc, &a_mc };
            hipLaunchCooperativeKernel((const void*)bigru_steps_fused,
                                       dim3(256), dim3(256), kargs, 0, stream);
        }
    }

    bigru_fc<<<NBAT, 256, 0, stream>>>(enc, fc_w, fc_b, out);
}

// Round 8
// 4301.297 us; speedup vs baseline: 1.1343x; 1.1343x over previous
//
#include <hip/hip_runtime.h>
#include <hip/hip_bf16.h>
#include <hip/hip_fp16.h>
#include <math.h>

#define HH    1024
#define TT    64
#define NBAT  256
#define G3    3072
#define IN0   150
#define IN0P  160   // padded K for layer 0
#define NCLS  60
#define ENC_W 2048

typedef float  f32x4 __attribute__((ext_vector_type(4)));
typedef short  s16x8 __attribute__((ext_vector_type(8)));

#define GLOAD16(gsrc, ldst) \
  __builtin_amdgcn_global_load_lds((const __attribute__((address_space(1))) unsigned int*)(gsrc), \
                                   (__attribute__((address_space(3))) unsigned int*)(ldst), 16, 0, 0)

static __device__ inline short f2bf(float f) {
    __hip_bfloat16 h = __float2bfloat16(f);
    return *(short*)&h;
}

// ---------------- BatchNorm stats ----------------
__global__ void bigru_bn_stats(const float* __restrict__ x,
                               float* __restrict__ mean, float* __restrict__ istd) {
    int f = blockIdx.x;
    int tid = threadIdx.x;
    double s = 0.0, s2 = 0.0;
    for (int i = tid; i < NBAT * TT; i += blockDim.x) {
        float v = x[(size_t)i * IN0 + f];
        s += v; s2 += (double)v * v;
    }
    __shared__ double sh[256], sh2[256];
    sh[tid] = s; sh2[tid] = s2;
    __syncthreads();
    for (int off = 128; off > 0; off >>= 1) {
        if (tid < off) { sh[tid] += sh[tid + off]; sh2[tid] += sh2[tid + off]; }
        __syncthreads();
    }
    if (tid == 0) {
        double m = sh[0] / (NBAT * TT);
        double var = sh2[0] / (NBAT * TT) - m * m;
        mean[f] = (float)m;
        istd[f] = (float)(1.0 / sqrt(var + 1e-5));
    }
}

// ---------------- BN apply -> padded bf16 [16384][160] ----------------
__global__ void bigru_bn_apply_bf16(const float* __restrict__ x,
                                    const float* __restrict__ mean, const float* __restrict__ istd,
                                    const float* __restrict__ gamma, const float* __restrict__ beta,
                                    short* __restrict__ xn) {
    int idx = blockIdx.x * blockDim.x + threadIdx.x;
    if (idx >= NBAT * TT * IN0P) return;
    int f = idx % IN0P;
    int r = idx / IN0P;
    float v = 0.f;
    if (f < IN0) v = (x[(size_t)r * IN0 + f] - mean[f]) * istd[f] * gamma[f] + beta[f];
    xn[idx] = f2bf(v);
}

// ---------------- Convert w_ih_0 [2][3072][150] -> padded bf16 [2][3072][160] ----
__global__ void bigru_cvt_wih0(const float* __restrict__ src, short* __restrict__ dst) {
    int idx = blockIdx.x * blockDim.x + threadIdx.x;
    if (idx >= 2 * G3 * IN0P) return;
    int f = idx % IN0P;
    int r = idx / IN0P;
    float v = (f < IN0) ? src[(size_t)r * IN0 + f] : 0.f;
    dst[idx] = f2bf(v);
}

// ---------------- Generic f32 -> bf16 convert (n % 4 == 0) ----------------
__global__ void bigru_cvt4(const float* __restrict__ src, short* __restrict__ dst, int n4) {
    int i = blockIdx.x * blockDim.x + threadIdx.x;
    if (i >= n4) return;
    float4 v = ((const float4*)src)[i];
    short4 o;
    o.x = f2bf(v.x); o.y = f2bf(v.y); o.z = f2bf(v.z); o.w = f2bf(v.w);
    ((short4*)dst)[i] = o;
}

// ---------------- Bulk gi GEMM: C[2][Mchunk][3072] = A @ W^T + b_ih (fp16 out) ----
__global__ __launch_bounds__(256)
void bigru_gi_gemm(const short* __restrict__ Abase, int ldA, int K,
                   const short* __restrict__ W,       // [2][3072][K]
                   const float* __restrict__ b_ih,    // [2][3072]
                   __half* __restrict__ gi,           // [2][Mchunk][3072] fp16
                   int t0, int Mchunk) {
    int d    = blockIdx.z;
    int col0 = blockIdx.x * 128;
    int row0 = blockIdx.y * 128;

    __shared__ short As[128][32];
    __shared__ short Bs[128][32];

    int tid  = threadIdx.x;
    int lane = tid & 63;
    int w    = tid >> 6;
    int wm   = w & 1, wn = w >> 1;

    f32x4 acc[4][4];
    #pragma unroll
    for (int i = 0; i < 4; ++i)
        #pragma unroll
        for (int j = 0; j < 4; ++j)
            acc[i][j] = (f32x4){0.f, 0.f, 0.f, 0.f};

    const short* Wd = W + (size_t)d * G3 * K;
    int sr = lane >> 2;
    int sc = (lane & 3) * 8;

    for (int k0 = 0; k0 < K; k0 += 32) {
        #pragma unroll
        for (int q = 0; q < 2; ++q) {
            int r  = w * 32 + q * 16 + sr;            // 0..127
            int gr = row0 + r;
            int tt = gr >> 8, n = gr & 255;
            const short* ga = Abase + (size_t)(n * TT + t0 + tt) * ldA + k0 + sc;
            GLOAD16(ga, &As[w * 32 + q * 16][0]);
            const short* gb = Wd + (size_t)(col0 + r) * K + k0 + sc;
            GLOAD16(gb, &Bs[w * 32 + q * 16][0]);
        }
        __syncthreads();

        int fr = lane & 15, fq = (lane >> 4) * 8;
        s16x8 a[4], b[4];
        #pragma unroll
        for (int i = 0; i < 4; ++i) a[i] = *(const s16x8*)&As[wm * 64 + i * 16 + fr][fq];
        #pragma unroll
        for (int j = 0; j < 4; ++j) b[j] = *(const s16x8*)&Bs[wn * 64 + j * 16 + fr][fq];
        #pragma unroll
        for (int i = 0; i < 4; ++i)
            #pragma unroll
            for (int j = 0; j < 4; ++j)
                acc[i][j] = __builtin_amdgcn_mfma_f32_16x16x32_bf16(a[i], b[j], acc[i][j], 0, 0, 0);
        __syncthreads();
    }

    int fr = lane & 15, quad = lane >> 4;
    #pragma unroll
    for (int j = 0; j < 4; ++j) {
        int c = col0 + wn * 64 + j * 16 + fr;
        float bias = b_ih[d * G3 + c];
        #pragma unroll
        for (int i = 0; i < 4; ++i) {
            #pragma unroll
            for (int reg = 0; reg < 4; ++reg) {
                int r = row0 + wm * 64 + i * 16 + quad * 4 + reg;
                gi[((size_t)d * Mchunk + r) * G3 + c] = __float2half(acc[i][j][reg] + bias);
            }
        }
    }
}

// ---------------- Per-timestep recurrence kernel (v8) ----------------
// ONE plain launch per step (coherence handled by the command processor
// between dependent launches — replaces the persistent kernel's per-step
// agent-scope wb/inv/poll, which v5/v6/v7 isolated as the ~13us/step floor).
// Inner structure = v7 verbatim: 256 blocks x 256 threads (4 waves),
// wave owns 32 rows (B fragment feeds 2 MFMAs), 96 KiB swizzled W LDS
// (staged per launch, L2-resident across steps), per-wave A-DMA ring
// 4 slots x 2KB, steady vmcnt(4), drain (2)/(0) at c=30/31. fp16 gi.
__global__ __launch_bounds__(256, 1)
void bigru_step(const short* __restrict__ w_hh,     // [2][3072][1024] bf16
                const float* __restrict__ b_hh,     // [2][3072]
                const __half* __restrict__ gi,      // [2][Mchunk][3072] fp16
                float* __restrict__ h,              // [2][256][1024] fp32 master
                const short* __restrict__ hbf_in,   // [2][256][1024] bf16
                short* __restrict__ hbf_out,        // [2][256][1024] bf16
                float* __restrict__ enc,            // non-null only on last layer
                short* __restrict__ enc_bf,         // null on last layer
                int t, int ttl, int Mchunk) {
    __shared__ short Ws[48 * 1024];     // 96 KiB W slice
    __shared__ short As[4][4][1024];    // 32 KiB A ring: 4 waves x 4 slots x 2KB

    int b   = blockIdx.x;
    int d   = b & 1;
    int mt  = (b >> 1) & 1;
    int ct  = b >> 2;              // 0..63

    int tid  = threadIdx.x;
    int lane = tid & 63;
    int w    = tid >> 6;           // 0..3
    int fr   = lane & 15;
    int quad = lane >> 4;
    int sw   = fr & 7;

    int j0 = ct * 16;
    int row_base = mt * 128 + w * 32;   // wave owns 32 rows
    int jcol = j0 + fr;

    const short* Wd = w_hh + (size_t)d * G3 * HH;

    // ---- stage W slice into LDS (pre-swizzled source, linear dest) ----
    #pragma unroll
    for (int q = 0; q < 24; ++q) {
        int c  = w * 24 + q;               // 0..95
        int rr = c >> 1, kh = c & 1;       // rr: wrow 0..47, kh: half-row
        int g  = rr >> 4, jc = rr & 15;
        const short* src = Wd + (size_t)(g * HH + j0 + jc) * HH
                         + (size_t)(kh * 64 + (lane ^ (rr & 7))) * 8;
        GLOAD16(src, &Ws[rr * 1024 + kh * 512]);
    }

    // ---- per-lane pre-swizzled A source mapping (linear DMA dest decode) ----
    int l0 = lane & 1, l1 = (lane >> 1) & 1, l2 = (lane >> 2) & 1;
    int l3 = (lane >> 3) & 1, l4 = (lane >> 4) & 1, l5 = (lane >> 5) & 1;
    int arow = (l2 ^ l4) | (l3 << 1) | (l4 << 2) | (l5 << 3);   // 0..15
    int akb  = (l0 ^ l2 ^ l4) | ((l1 ^ l3) << 1);               // 0..3
    const short* hb = hbf_in + (size_t)d * NBAT * HH;
    const short* asrc0 = hb + (size_t)(row_base + arow) * HH + (size_t)akb * 8;
    const short* asrc1 = hb + (size_t)(row_base + 16 + arow) * HH + (size_t)akb * 8;

    // ---- gi (fp16), h master, biases — issued under W-staging latency ----
    float gir[2][4], giz[2][4], gin[2][4], hreg[2][4];
    {
        size_t gb = ((size_t)d * Mchunk + (size_t)ttl * NBAT) * G3 + jcol;
        #pragma unroll
        for (int hh = 0; hh < 2; ++hh)
            #pragma unroll
            for (int r = 0; r < 4; ++r) {
                int n = row_base + hh * 16 + quad * 4 + r;
                size_t gg = gb + (size_t)n * G3;
                gir[hh][r] = __half2float(gi[gg]);
                giz[hh][r] = __half2float(gi[gg + HH]);
                gin[hh][r] = __half2float(gi[gg + 2 * HH]);
                hreg[hh][r] = h[((size_t)d * NBAT + n) * HH + jcol];
            }
    }
    float bhr = b_hh[d * G3 + jcol];
    float bhz = b_hh[d * G3 + HH + jcol];
    float bhn = b_hh[d * G3 + 2 * HH + jcol];

    __syncthreads();   // drains W DMA (+ all scalar loads): FIFO empty here

    f32x4 acc[2][3];
    #pragma unroll
    for (int hh = 0; hh < 2; ++hh)
        #pragma unroll
        for (int g = 0; g < 3; ++g)
            acc[hh][g] = (f32x4){0.f, 0.f, 0.f, 0.f};

    // prologue: 3 slots (6 DMA instrs) in flight
    #pragma unroll
    for (int c = 0; c < 3; ++c) {
        GLOAD16(asrc0 + c * 32, &As[w][c][0]);
        GLOAD16(asrc1 + c * 32, &As[w][c][512]);
    }

    int rd_off = (fr * 64 + quad * 16) ^ ((fr & 7) << 4);   // swizzled A read (bytes)

    #pragma unroll
    for (int c = 0; c < 32; ++c) {
        // slot c complete when outstanding <= 2*min(31-c,2)
        if (c < 30)       asm volatile("s_waitcnt vmcnt(4)");
        else if (c == 30) asm volatile("s_waitcnt vmcnt(2)");
        else              asm volatile("s_waitcnt vmcnt(0)");
        __builtin_amdgcn_sched_barrier(0);
        const char* slot = (const char*)&As[w][c & 3][0];
        s16x8 a0 = *(const s16x8*)(slot + rd_off);
        s16x8 a1 = *(const s16x8*)(slot + 1024 + rd_off);
        int ks = c * 4 + quad;
        #pragma unroll
        for (int g = 0; g < 3; ++g) {
            s16x8 bg = *(const s16x8*)&Ws[(g * 16 + fr) * 1024 + ((ks ^ sw) << 3)];
            acc[0][g] = __builtin_amdgcn_mfma_f32_16x16x32_bf16(a0, bg, acc[0][g], 0, 0, 0);
            acc[1][g] = __builtin_amdgcn_mfma_f32_16x16x32_bf16(a1, bg, acc[1][g], 0, 0, 0);
        }
        __builtin_amdgcn_sched_barrier(0);
        if (c + 3 < 32) {
            GLOAD16(asrc0 + (c + 3) * 32, &As[w][(c + 3) & 3][0]);
            GLOAD16(asrc1 + (c + 3) * 32, &As[w][(c + 3) & 3][512]);
        }
    }

    // ---- gates + state update (2 row-frags) ----
    short* ho = hbf_out + (size_t)d * NBAT * HH;
    #pragma unroll
    for (int hh = 0; hh < 2; ++hh) {
        #pragma unroll
        for (int r = 0; r < 4; ++r) {
            int n = row_base + hh * 16 + quad * 4 + r;
            float hrv = acc[hh][0][r] + bhr;
            float hzv = acc[hh][1][r] + bhz;
            float hnv = acc[hh][2][r] + bhn;
            float rg = 1.f / (1.f + __expf(-(gir[hh][r] + hrv)));
            float zg = 1.f / (1.f + __expf(-(giz[hh][r] + hzv)));
            float ng = tanhf(gin[hh][r] + rg * hnv);
            float hnew = (1.f - zg) * ng + zg * hreg[hh][r];
            h[((size_t)d * NBAT + n) * HH + jcol] = hnew;
            ho[(size_t)n * HH + jcol] = f2bf(hnew);
            size_t eidx = ((size_t)n * TT + t) * ENC_W + (size_t)d * HH + jcol;
            if (enc_bf) enc_bf[eidx] = f2bf(hnew);
            if (enc)    enc[eidx]    = hnew;
        }
    }
}

// ---------------- FC head ----------------
__global__ void bigru_fc(const float* __restrict__ enc, const float* __restrict__ fc_w,
                         const float* __restrict__ fc_b, float* __restrict__ out) {
    int n = blockIdx.x;
    int tid = threadIdx.x;
    __shared__ float hbuf[ENC_W];
    for (int k = tid; k < ENC_W; k += blockDim.x)
        hbuf[k] = enc[(size_t)n * TT * ENC_W + (size_t)(TT - 1) * ENC_W + k];
    __syncthreads();
    if (tid < NCLS) {
        float acc = fc_b[tid];
        for (int k = 0; k < ENC_W; ++k)
            acc += hbuf[k] * fc_w[(size_t)tid * ENC_W + k];
        out[(size_t)n * NCLS + tid] = acc;
    }
}

extern "C" void kernel_launch(void* const* d_in, const int* in_sizes, int n_in,
                              void* d_out, int out_size, void* d_ws, size_t ws_size,
                              hipStream_t stream) {
    const float* x        = (const float*)d_in[0];
    const float* bn_gamma = (const float*)d_in[1];
    const float* bn_beta  = (const float*)d_in[2];
    const float* w_ih[3]  = {(const float*)d_in[3], (const float*)d_in[7],  (const float*)d_in[11]};
    const float* w_hh[3]  = {(const float*)d_in[4], (const float*)d_in[8],  (const float*)d_in[12]};
    const float* b_ih[3]  = {(const float*)d_in[5], (const float*)d_in[9],  (const float*)d_in[13]};
    const float* b_hh[3]  = {(const float*)d_in[6], (const float*)d_in[10], (const float*)d_in[14]};
    const float* fc_w     = (const float*)d_in[15];
    const float* fc_b     = (const float*)d_in[16];

    float* out = (float*)d_out;
    float* enc = out + NBAT * NCLS;                       // [256][64][2048] fp32

    // ---- workspace bump allocator (256B aligned) ----
    char* base = (char*)d_ws;
    size_t off = 0;
    auto alloc = [&](size_t bytes) {
        void* p = base + off;
        off += (bytes + 255) & ~(size_t)255;
        return p;
    };
    float* mean      = (float*)alloc(IN0 * 4);
    float* istd      = (float*)alloc(IN0 * 4);
    short* xn_bf     = (short*)alloc((size_t)NBAT * TT * IN0P * 2);
    short* wih0_bf   = (short*)alloc((size_t)2 * G3 * IN0P * 2);
    short* wih_bf    = (short*)alloc((size_t)2 * G3 * ENC_W * 2);
    short* whh_bf    = (short*)alloc((size_t)2 * G3 * HH * 2);
    float* h         = (float*)alloc((size_t)2 * NBAT * HH * 4);
    short* hbf       = (short*)alloc((size_t)2 * 2 * NBAT * HH * 2);  // double buffer
    short* enc_bf    = (short*)alloc((size_t)NBAT * TT * ENC_W * 2);
    size_t fixed = off;

    // pick largest Tc whose fp16 gi chunk fits in remaining ws
    int Tc = 1;
    for (int cand : {16, 8, 4, 2, 1}) {
        size_t gi_bytes = (size_t)2 * NBAT * cand * G3 * 2;
        if (fixed + gi_bytes + 1024 <= ws_size) { Tc = cand; break; }
    }
    __half* gi = (__half*)alloc((size_t)2 * NBAT * Tc * G3 * 2);
    int Mchunk = NBAT * Tc;

    // ---- BN ----
    bigru_bn_stats<<<IN0, 256, 0, stream>>>(x, mean, istd);
    bigru_bn_apply_bf16<<<(NBAT * TT * IN0P + 255) / 256, 256, 0, stream>>>(
        x, mean, istd, bn_gamma, bn_beta, xn_bf);

    // ---- weight conversions (layer-0 padded) ----
    bigru_cvt_wih0<<<(2 * G3 * IN0P + 255) / 256, 256, 0, stream>>>(w_ih[0], wih0_bf);

    for (int l = 0; l < 3; ++l) {
        if (l > 0) {
            int n4 = (2 * G3 * ENC_W) / 4;
            bigru_cvt4<<<(n4 + 255) / 256, 256, 0, stream>>>(w_ih[l], wih_bf, n4);
        }
        {
            int n4 = (2 * G3 * HH) / 4;
            bigru_cvt4<<<(n4 + 255) / 256, 256, 0, stream>>>(w_hh[l], whh_bf, n4);
        }
        hipMemsetAsync(h, 0, (size_t)2 * NBAT * HH * 4, stream);
        hipMemsetAsync(hbf, 0, (size_t)2 * 2 * NBAT * HH * 2, stream);

        const short* Abase = (l == 0) ? xn_bf : enc_bf;
        int ldA = (l == 0) ? IN0P : ENC_W;
        int K   = (l == 0) ? IN0P : ENC_W;
        const short* W = (l == 0) ? wih0_bf : wih_bf;
        float* enc_out   = (l == 2) ? enc : nullptr;
        short* encbf_out = (l == 2) ? nullptr : enc_bf;

        for (int t0 = 0; t0 < TT; t0 += Tc) {
            bigru_gi_gemm<<<dim3(G3 / 128, Mchunk / 128, 2), 256, 0, stream>>>(
                Abase, ldA, K, W, b_ih[l], gi, t0, Mchunk);

            for (int tt = 0; tt < Tc; ++tt) {
                int t = t0 + tt;
                const short* hin = hbf + (size_t)(t & 1) * 2 * NBAT * HH;
                short*       hout = hbf + (size_t)((t + 1) & 1) * 2 * NBAT * HH;
                bigru_step<<<dim3(256), 256, 0, stream>>>(
                    whh_bf, b_hh[l], gi, h, hin, hout,
                    enc_out, encbf_out, t, tt, Mchunk);
            }
        }
    }

    bigru_fc<<<NBAT, 256, 0, stream>>>(enc, fc_w, fc_b, out);
}